// Round 3
// baseline (2733.070 us; speedup 1.0000x reference)
//
#include <hip/hip_runtime.h>
#include <hip/hip_bf16.h>
#include <math.h>

// ---------------------------------------------------------------------------
// Mamba2 forward. Split-bf16 MFMA GEMMs (fp32-accurate), fp32 scaffold.
// Shapes: B=2 L=4096 DM=1024 DI=2048 DS=64 HD=64 NH=32 DCONV=4
// D_CONV_CH=2176, D_IN_PROJ=4256 (z:2048 | xBC:2176 | dt:32)
// Pipeline:
//   K1 gemm_bf16split: zx[m,0:4224] = x @ W_in[:,0:4224]   (z + xBC)
//   K2 dt_kernel     : dt[m,h] = softplus(x[m]·W_in[:,4224+h] + bias), dA=exp(dt*A)
//   K3 conv_kernel   : conv[m,c] = silu(causal depthwise conv4 over xBC + b)
//   K4 scan_kernel   : sequential SSM scan; wave per (b,h,p), lane = state n
//   K5 norm_kernel   : g = y*silu(z); RMSNorm(g)*w  (in place)
//   K6 gemm_bf16split: out = yn @ W_out
// Split-bf16: a = hi + lo (both bf16, RNE); C += Ahi*Bhi + Ahi*Blo + Alo*Bhi.
// Residual error ~2^-18 relative (lo*lo dropped) => fp32-equivalent output.
// ws (floats): zx[8192*4224] | conv[8192*2176] | dt[262144] | dA[262144]
//   = 211,812,352 bytes total.
// ---------------------------------------------------------------------------

#define LSTRIDE 4224   // zx row stride (z + xBC, dt columns excluded)
#define CSTRIDE 2176   // conv row stride
#define MROWS   8192   // B*L
#define LPAD    40     // LDS row stride (ushorts): 80B, 16B-aligned, 2-way-free banks

typedef __attribute__((ext_vector_type(8))) short bf16x8;
typedef __attribute__((ext_vector_type(4))) float f32x4;

static __device__ __forceinline__ ushort f2bf_rne(float f) {
  unsigned u = __float_as_uint(f);
  unsigned r = (u + 0x7fffu + ((u >> 16) & 1u)) >> 16;
  return (ushort)r;
}
static __device__ __forceinline__ float bf2f(ushort u) {
  return __uint_as_float(((unsigned)u) << 16);
}

// ------- K1/K6: split-bf16 MFMA GEMM, 128x128 tile, 4 waves of 64x64 -------
// A: [M][K] fp32 row-major (lda), B: [K][N] fp32 row-major (ldb), C: [M][N] (ldc).
// M%128==0, N%128==0, K%32==0 required.
__global__ __launch_bounds__(256) void gemm_bf16split(
    const float* __restrict__ A, const float* __restrict__ B,
    float* __restrict__ C, int K, int lda, int ldb, int ldc) {
  __shared__ ushort Ah[128][LPAD];  // [row][k]
  __shared__ ushort Al[128][LPAD];
  __shared__ ushort Bh[128][LPAD];  // [n][k] (transposed)
  __shared__ ushort Bl[128][LPAD];

  const int tid  = threadIdx.x;
  const int lane = tid & 63;
  const int wid  = tid >> 6;
  const int wm   = wid >> 1;        // wave row 0..1 (64 rows each)
  const int wn   = wid & 1;         // wave col 0..1 (64 cols each)
  const int bm   = blockIdx.y * 128;
  const int bn   = blockIdx.x * 128;

  // A staging map: thread -> row r, col group (4 float4 = 16 k)
  const int ar  = tid >> 1;              // 0..127
  const int acg = (tid & 1) * 16;        // 0 or 16
  // B staging map: thread -> col n, k half (16 k scalars)
  const int bnt = tid & 127;             // 0..127
  const int bkg = (tid >> 7) * 16;       // 0 or 16

  const int lr  = lane & 15;             // frag row/col within 16
  const int lk8 = (lane >> 4) * 8;       // frag k base
  const int lq4 = (lane >> 4) * 4;       // C/D row base

  f32x4 acc[4][4];
  #pragma unroll
  for (int m = 0; m < 4; ++m)
    #pragma unroll
    for (int n = 0; n < 4; ++n) acc[m][n] = (f32x4)0.f;

  for (int k0 = 0; k0 < K; k0 += 32) {
    // ---- global loads (coalesced) ----
    float4 av[4];
    #pragma unroll
    for (int f = 0; f < 4; ++f)
      av[f] = *(const float4*)(A + (size_t)(bm + ar) * lda + k0 + acg + f * 4);
    float bv[16];
    #pragma unroll
    for (int kk = 0; kk < 16; ++kk)
      bv[kk] = B[(size_t)(k0 + bkg + kk) * ldb + bn + bnt];

    __syncthreads();   // previous iter's frag reads done before overwrite

    // ---- split + LDS write ----
    #pragma unroll
    for (int f = 0; f < 4; ++f) {
      const int col = acg + f * 4;
      float v[4] = {av[f].x, av[f].y, av[f].z, av[f].w};
      ushort h[4], l[4];
      #pragma unroll
      for (int q = 0; q < 4; ++q) {
        h[q] = f2bf_rne(v[q]);
        l[q] = f2bf_rne(v[q] - bf2f(h[q]));
      }
      *(ushort4*)&Ah[ar][col] = make_ushort4(h[0], h[1], h[2], h[3]);
      *(ushort4*)&Al[ar][col] = make_ushort4(l[0], l[1], l[2], l[3]);
    }
    {
      ushort h[16], l[16];
      #pragma unroll
      for (int kk = 0; kk < 16; ++kk) {
        h[kk] = f2bf_rne(bv[kk]);
        l[kk] = f2bf_rne(bv[kk] - bf2f(h[kk]));
      }
      #pragma unroll
      for (int f = 0; f < 4; ++f) {
        *(ushort4*)&Bh[bnt][bkg + f * 4] = make_ushort4(h[f*4], h[f*4+1], h[f*4+2], h[f*4+3]);
        *(ushort4*)&Bl[bnt][bkg + f * 4] = make_ushort4(l[f*4], l[f*4+1], l[f*4+2], l[f*4+3]);
      }
    }
    __syncthreads();

    // ---- fragment reads ----
    bf16x8 fah[4], fal[4], fbh[4], fbl[4];
    #pragma unroll
    for (int m = 0; m < 4; ++m) {
      const int row = wm * 64 + m * 16 + lr;
      fah[m] = *(const bf16x8*)&Ah[row][lk8];
      fal[m] = *(const bf16x8*)&Al[row][lk8];
    }
    #pragma unroll
    for (int n = 0; n < 4; ++n) {
      const int col = wn * 64 + n * 16 + lr;
      fbh[n] = *(const bf16x8*)&Bh[col][lk8];
      fbl[n] = *(const bf16x8*)&Bl[col][lk8];
    }
    // ---- 3-pass MFMA ----
    #pragma unroll
    for (int m = 0; m < 4; ++m)
      #pragma unroll
      for (int n = 0; n < 4; ++n) {
        acc[m][n] = __builtin_amdgcn_mfma_f32_16x16x32_bf16(fah[m], fbh[n], acc[m][n], 0, 0, 0);
        acc[m][n] = __builtin_amdgcn_mfma_f32_16x16x32_bf16(fah[m], fbl[n], acc[m][n], 0, 0, 0);
        acc[m][n] = __builtin_amdgcn_mfma_f32_16x16x32_bf16(fal[m], fbh[n], acc[m][n], 0, 0, 0);
      }
  }

  // ---- C write: row=(lane>>4)*4+q, col=lane&15 (m89-verified) ----
  #pragma unroll
  for (int m = 0; m < 4; ++m) {
    const int rbase = bm + wm * 64 + m * 16 + lq4;
    #pragma unroll
    for (int n = 0; n < 4; ++n) {
      const int col = bn + wn * 64 + n * 16 + lr;
      #pragma unroll
      for (int q = 0; q < 4; ++q)
        C[(size_t)(rbase + q) * ldc + col] = acc[m][n][q];
    }
  }
}

// ----------------- K2: dt columns (fp32 dot) + softplus + dA ---------------
__global__ __launch_bounds__(256) void dt_kernel(
    const float* __restrict__ x, const float* __restrict__ W_in,
    const float* __restrict__ dt_bias, const float* __restrict__ A_log,
    float* __restrict__ dt_buf, float* __restrict__ dA_buf) {
  __shared__ float xs[1024];
  __shared__ float red[8][32];
  const int m = blockIdx.x, tid = threadIdx.x;
  const float* xr = x + (size_t)m * 1024;
  *(float4*)&xs[tid * 4] = *(const float4*)&xr[tid * 4];
  __syncthreads();
  const int h = tid & 31, part = tid >> 5;
  const float* w = W_in + 4224 + h;
  float acc = 0.f;
  const int kb = part * 128;
  #pragma unroll 4
  for (int k = kb; k < kb + 128; ++k) acc = fmaf(xs[k], w[(size_t)k * 4256], acc);
  red[part][h] = acc;
  __syncthreads();
  if (tid < 32) {
    float v = 0.f;
    #pragma unroll
    for (int p = 0; p < 8; ++p) v += red[p][tid];
    v += dt_bias[tid];
    float sp = v > 20.f ? v : log1pf(expf(v));
    float An = -expf(A_log[tid]);
    dt_buf[(size_t)m * 32 + tid] = sp;
    dA_buf[(size_t)m * 32 + tid] = expf(sp * An);
  }
}

// ----------------- K3: causal depthwise conv4 + bias + silu ----------------
__global__ __launch_bounds__(256) void conv_kernel(
    const float* __restrict__ zx, const float* __restrict__ cw,
    const float* __restrict__ cb, float* __restrict__ conv) {
  const int c = blockIdx.x * 256 + threadIdx.x;
  if (c >= CSTRIDE) return;
  const int m = blockIdx.y;
  const int l = m & 4095;              // within-batch index
  float acc = cb[c];
  const float* src = zx + (size_t)m * LSTRIDE + 2048 + c;
  #pragma unroll
  for (int k = 0; k < 4; ++k) {
    int lk = l - 3 + k;
    if (lk >= 0) acc = fmaf(src[(size_t)(k - 3) * LSTRIDE], cw[c * 4 + k], acc);
  }
  float s = acc / (1.f + expf(-acc));  // silu
  conv[(size_t)m * CSTRIDE + c] = s;
}

// ----------------- K4: sequential SSM scan, wave per (b,h,p) ---------------
__global__ __launch_bounds__(256) void scan_kernel(
    const float* __restrict__ conv, const float* __restrict__ dt_buf,
    const float* __restrict__ dA_buf, const float* __restrict__ Dv,
    float* __restrict__ yout) {
  const int wid  = blockIdx.x * 4 + (threadIdx.x >> 6);
  const int lane = threadIdx.x & 63;
  const int b = wid >> 11;
  const int h = (wid >> 6) & 31;
  const int p = wid & 63;
  const size_t m0 = (size_t)b * 4096;
  const float* cx  = conv + m0 * CSTRIDE + h * 64 + p;
  const float* cB  = conv + m0 * CSTRIDE + 2048 + lane;
  const float* cC  = cB + 64;
  const float* cdA = dA_buf + m0 * 32 + h;
  const float* cdt = dt_buf + m0 * 32 + h;
  float* yo = yout + m0 * LSTRIDE + 2048 + h * 64 + p;
  const float Dh = Dv[h];
  float s = 0.f;
  #pragma unroll 2
  for (int t = 0; t < 4096; ++t) {
    float xv  = cx[(size_t)t * CSTRIDE];
    float Bv  = cB[(size_t)t * CSTRIDE];
    float Cv  = cC[(size_t)t * CSTRIDE];
    float dAv = cdA[t * 32];
    float dtv = cdt[t * 32];
    s = fmaf(s, dAv, dtv * xv * Bv);
    float prod = s * Cv;
    #pragma unroll
    for (int msk = 1; msk < 64; msk <<= 1) prod += __shfl_xor(prod, msk, 64);
    if (lane == 0) yo[(size_t)t * LSTRIDE] = fmaf(Dh, xv, prod);
  }
}

// ----------------- K5: gate with silu(z) + RMSNorm (in place) --------------
__global__ __launch_bounds__(256) void norm_kernel(
    float* __restrict__ zx, const float* __restrict__ nw) {
  const int row = blockIdx.x, tid = threadIdx.x;
  float* z = zx + (size_t)row * LSTRIDE;
  float* y = z + 2048;
  float g[8];
  float ss = 0.f;
  #pragma unroll
  for (int j = 0; j < 2; ++j) {
    const int col = j * 1024 + tid * 4;
    float4 yv = *(const float4*)&y[col];
    float4 zv = *(const float4*)&z[col];
    float gs[4];
    gs[0] = yv.x * (zv.x / (1.f + expf(-zv.x)));
    gs[1] = yv.y * (zv.y / (1.f + expf(-zv.y)));
    gs[2] = yv.z * (zv.z / (1.f + expf(-zv.z)));
    gs[3] = yv.w * (zv.w / (1.f + expf(-zv.w)));
    #pragma unroll
    for (int q = 0; q < 4; ++q) { g[j * 4 + q] = gs[q]; ss += gs[q] * gs[q]; }
  }
  #pragma unroll
  for (int msk = 1; msk < 64; msk <<= 1) ss += __shfl_xor(ss, msk, 64);
  __shared__ float sred[4];
  if ((tid & 63) == 0) sred[tid >> 6] = ss;
  __syncthreads();
  ss = sred[0] + sred[1] + sred[2] + sred[3];
  const float scale = rsqrtf(ss * (1.f / 2048.f) + 1e-5f);
  #pragma unroll
  for (int j = 0; j < 2; ++j) {
    const int col = j * 1024 + tid * 4;
    float4 ov;
    ov.x = g[j * 4 + 0] * scale * nw[col + 0];
    ov.y = g[j * 4 + 1] * scale * nw[col + 1];
    ov.z = g[j * 4 + 2] * scale * nw[col + 2];
    ov.w = g[j * 4 + 3] * scale * nw[col + 3];
    *(float4*)&y[col] = ov;
  }
}

// ---------------------------------------------------------------------------
extern "C" void kernel_launch(void* const* d_in, const int* in_sizes, int n_in,
                              void* d_out, int out_size, void* d_ws, size_t ws_size,
                              hipStream_t stream) {
  const float* x       = (const float*)d_in[0];
  const float* W_in    = (const float*)d_in[1];
  const float* conv_w  = (const float*)d_in[2];
  const float* conv_b  = (const float*)d_in[3];
  const float* dt_bias = (const float*)d_in[4];
  const float* A_log   = (const float*)d_in[5];
  const float* Dv      = (const float*)d_in[6];
  const float* nw      = (const float*)d_in[7];
  const float* W_out   = (const float*)d_in[8];
  float* out = (float*)d_out;

  float* zx   = (float*)d_ws;                       // 8192*4224
  float* conv = zx + (size_t)MROWS * LSTRIDE;       // 8192*2176
  float* dtb  = conv + (size_t)MROWS * CSTRIDE;     // 262,144
  float* dAb  = dtb + (size_t)MROWS * 32;           // 262,144

  // K1: zx = x @ W_in[:, 0:4224]  (split-bf16 MFMA)
  gemm_bf16split<<<dim3(33, 64), 256, 0, stream>>>(x, W_in, zx, 1024, 1024, 4256, LSTRIDE);
  // K2: dt columns + softplus + dA (fp32 — precision-critical exp path)
  dt_kernel<<<MROWS, 256, 0, stream>>>(x, W_in, dt_bias, A_log, dtb, dAb);
  // K3: depthwise causal conv + silu
  conv_kernel<<<dim3(9, MROWS), 256, 0, stream>>>(zx, conv_w, conv_b, conv);
  // K4: SSM scan -> y into zx cols [2048,4096)
  scan_kernel<<<1024, 256, 0, stream>>>(conv, dtb, dAb, Dv, zx);
  // K5: gate + RMSNorm in place
  norm_kernel<<<MROWS, 256, 0, stream>>>(zx, nw);
  // K6: out = yn @ W_out  (split-bf16 MFMA)
  gemm_bf16split<<<dim3(8, 64), 256, 0, stream>>>(zx + 2048, W_out, out, 2048, LSTRIDE, 1024, 1024);
}

// Round 4
// 1024.780 us; speedup vs baseline: 2.6670x; 2.6670x over previous
//
#include <hip/hip_runtime.h>
#include <hip/hip_bf16.h>
#include <math.h>

// ---------------------------------------------------------------------------
// Mamba2 forward. Split-bf16 MFMA GEMMs + chunked (SSD) scan in fp32.
// Shapes: B=2 L=4096 DM=1024 DI=2048 DS=64 HD=64 NH=32 DCONV=4
// D_CONV_CH=2176, D_IN_PROJ=4256 (z:2048 | xBC:2176 | dt:32)
// Pipeline:
//   K1 gemm_bf16split: zx[m,0:4224] = x @ W_in[:,0:4224]
//   K2 dt_kernel     : dt=softplus(x·w+b); dtA = dt*A   (A = -exp(A_log))
//   K3 conv_kernel   : conv = silu(depthwise causal conv4 + bias)
//   K4a chunk_intra  : per (b,h,c) tile Q=128: la=cumsum(dtA);
//                      W=(C@B^T)∘mask; Y_intra=W@X -> zx; S_c=(B·f)^T@X
//   K4b state_scan   : sin(c+1)=exp(laQ_c)*sin(c)+S_c  (in-place: slot c := sin(c))
//   K4c chunk_out    : zx_y += exp(la_i)*C@sin + D*x
//   K4f scan_kernel_fb: old serial scan (fallback if ws too small)
//   K5 norm_kernel   : g=y*silu(z); RMSNorm(g)*w (in place)
//   K6 gemm_bf16split: out = yn @ W_out
// ws (floats): zx[34,603,008] conv[17,825,792] dt[262,144] dtA[262,144]
//              S[8,388,608] la[262,144]  => 246,415,360 bytes (chunked path)
// ---------------------------------------------------------------------------

#define LSTRIDE 4224
#define CSTRIDE 2176
#define MROWS   8192
#define LPAD    40
#define QCH     128     // chunk length
#define NCH     32      // chunks per sequence

typedef __attribute__((ext_vector_type(8))) short bf16x8;
typedef __attribute__((ext_vector_type(4))) float f32x4;

static __device__ __forceinline__ ushort f2bf_rne(float f) {
  unsigned u = __float_as_uint(f);
  unsigned r = (u + 0x7fffu + ((u >> 16) & 1u)) >> 16;
  return (ushort)r;
}
static __device__ __forceinline__ float bf2f(ushort u) {
  return __uint_as_float(((unsigned)u) << 16);
}

// ------- K1/K6: split-bf16 MFMA GEMM, 128x128 tile, 4 waves of 64x64 -------
__global__ __launch_bounds__(256) void gemm_bf16split(
    const float* __restrict__ A, const float* __restrict__ B,
    float* __restrict__ C, int K, int lda, int ldb, int ldc) {
  __shared__ ushort Ah[128][LPAD];
  __shared__ ushort Al[128][LPAD];
  __shared__ ushort Bh[128][LPAD];
  __shared__ ushort Bl[128][LPAD];

  const int tid  = threadIdx.x;
  const int lane = tid & 63;
  const int wid  = tid >> 6;
  const int wm   = wid >> 1;
  const int wn   = wid & 1;
  const int bm   = blockIdx.y * 128;
  const int bn   = blockIdx.x * 128;

  const int ar  = tid >> 1;
  const int acg = (tid & 1) * 16;
  const int bnt = tid & 127;
  const int bkg = (tid >> 7) * 16;

  const int lr  = lane & 15;
  const int lk8 = (lane >> 4) * 8;
  const int lq4 = (lane >> 4) * 4;

  f32x4 acc[4][4];
  #pragma unroll
  for (int m = 0; m < 4; ++m)
    #pragma unroll
    for (int n = 0; n < 4; ++n) acc[m][n] = (f32x4)0.f;

  for (int k0 = 0; k0 < K; k0 += 32) {
    float4 av[4];
    #pragma unroll
    for (int f = 0; f < 4; ++f)
      av[f] = *(const float4*)(A + (size_t)(bm + ar) * lda + k0 + acg + f * 4);
    float bv[16];
    #pragma unroll
    for (int kk = 0; kk < 16; ++kk)
      bv[kk] = B[(size_t)(k0 + bkg + kk) * ldb + bn + bnt];

    __syncthreads();

    #pragma unroll
    for (int f = 0; f < 4; ++f) {
      const int col = acg + f * 4;
      float v[4] = {av[f].x, av[f].y, av[f].z, av[f].w};
      ushort h[4], l[4];
      #pragma unroll
      for (int q = 0; q < 4; ++q) {
        h[q] = f2bf_rne(v[q]);
        l[q] = f2bf_rne(v[q] - bf2f(h[q]));
      }
      *(ushort4*)&Ah[ar][col] = make_ushort4(h[0], h[1], h[2], h[3]);
      *(ushort4*)&Al[ar][col] = make_ushort4(l[0], l[1], l[2], l[3]);
    }
    {
      ushort h[16], l[16];
      #pragma unroll
      for (int kk = 0; kk < 16; ++kk) {
        h[kk] = f2bf_rne(bv[kk]);
        l[kk] = f2bf_rne(bv[kk] - bf2f(h[kk]));
      }
      #pragma unroll
      for (int f = 0; f < 4; ++f) {
        *(ushort4*)&Bh[bnt][bkg + f * 4] = make_ushort4(h[f*4], h[f*4+1], h[f*4+2], h[f*4+3]);
        *(ushort4*)&Bl[bnt][bkg + f * 4] = make_ushort4(l[f*4], l[f*4+1], l[f*4+2], l[f*4+3]);
      }
    }
    __syncthreads();

    bf16x8 fah[4], fal[4], fbh[4], fbl[4];
    #pragma unroll
    for (int m = 0; m < 4; ++m) {
      const int row = wm * 64 + m * 16 + lr;
      fah[m] = *(const bf16x8*)&Ah[row][lk8];
      fal[m] = *(const bf16x8*)&Al[row][lk8];
    }
    #pragma unroll
    for (int n = 0; n < 4; ++n) {
      const int col = wn * 64 + n * 16 + lr;
      fbh[n] = *(const bf16x8*)&Bh[col][lk8];
      fbl[n] = *(const bf16x8*)&Bl[col][lk8];
    }
    #pragma unroll
    for (int m = 0; m < 4; ++m)
      #pragma unroll
      for (int n = 0; n < 4; ++n) {
        acc[m][n] = __builtin_amdgcn_mfma_f32_16x16x32_bf16(fah[m], fbh[n], acc[m][n], 0, 0, 0);
        acc[m][n] = __builtin_amdgcn_mfma_f32_16x16x32_bf16(fah[m], fbl[n], acc[m][n], 0, 0, 0);
        acc[m][n] = __builtin_amdgcn_mfma_f32_16x16x32_bf16(fal[m], fbh[n], acc[m][n], 0, 0, 0);
      }
  }

  #pragma unroll
  for (int m = 0; m < 4; ++m) {
    const int rbase = bm + wm * 64 + m * 16 + lq4;
    #pragma unroll
    for (int n = 0; n < 4; ++n) {
      const int col = bn + wn * 64 + n * 16 + lr;
      #pragma unroll
      for (int q = 0; q < 4; ++q)
        C[(size_t)(rbase + q) * ldc + col] = acc[m][n][q];
    }
  }
}

// ----------------- K2: dt columns (fp32 dot) + softplus + dtA --------------
__global__ __launch_bounds__(256) void dt_kernel(
    const float* __restrict__ x, const float* __restrict__ W_in,
    const float* __restrict__ dt_bias, const float* __restrict__ A_log,
    float* __restrict__ dt_buf, float* __restrict__ dtA_buf) {
  __shared__ float xs[1024];
  __shared__ float red[8][32];
  const int m = blockIdx.x, tid = threadIdx.x;
  const float* xr = x + (size_t)m * 1024;
  *(float4*)&xs[tid * 4] = *(const float4*)&xr[tid * 4];
  __syncthreads();
  const int h = tid & 31, part = tid >> 5;
  const float* w = W_in + 4224 + h;
  float acc = 0.f;
  const int kb = part * 128;
  #pragma unroll 4
  for (int k = kb; k < kb + 128; ++k) acc = fmaf(xs[k], w[(size_t)k * 4256], acc);
  red[part][h] = acc;
  __syncthreads();
  if (tid < 32) {
    float v = 0.f;
    #pragma unroll
    for (int p = 0; p < 8; ++p) v += red[p][tid];
    v += dt_bias[tid];
    float sp = v > 20.f ? v : log1pf(expf(v));
    float An = -expf(A_log[tid]);
    dt_buf[(size_t)m * 32 + tid] = sp;
    dtA_buf[(size_t)m * 32 + tid] = sp * An;   // log(dA), <= 0
  }
}

// ----------------- K3: causal depthwise conv4 + bias + silu ----------------
__global__ __launch_bounds__(256) void conv_kernel(
    const float* __restrict__ zx, const float* __restrict__ cw,
    const float* __restrict__ cb, float* __restrict__ conv) {
  const int c = blockIdx.x * 256 + threadIdx.x;
  if (c >= CSTRIDE) return;
  const int m = blockIdx.y;
  const int l = m & 4095;
  float acc = cb[c];
  const float* src = zx + (size_t)m * LSTRIDE + 2048 + c;
  #pragma unroll
  for (int k = 0; k < 4; ++k) {
    int lk = l - 3 + k;
    if (lk >= 0) acc = fmaf(src[(size_t)(k - 3) * LSTRIDE], cw[c * 4 + k], acc);
  }
  float s = acc / (1.f + expf(-acc));
  conv[(size_t)m * CSTRIDE + c] = s;
}

// --------- K4a: intra-chunk tile (Q=128): la, W=(C@B^T)∘M, Y=W@X, S --------
// One block per (b,h,c). LDS layouts chosen conflict-free:
//  Xs[128][65]  ([t][p], pad65 -> (j+lane)%32 banks)
//  Bt/Ct[64][132] ([n][t], transposed; rows 528B = 16B aligned for f4 bcast)
//  Wt[128][68]  ([j][i], rows 272B aligned; f4 bcast reads)
__global__ __launch_bounds__(256) void chunk_intra(
    const float* __restrict__ conv, const float* __restrict__ dtb,
    const float* __restrict__ dtAb, float* __restrict__ zx,
    float* __restrict__ Sbuf, float* __restrict__ labuf) {
  __shared__ float Xs[128][65];
  __shared__ float Ct[64][132];
  __shared__ float Bt[64][132];
  __shared__ float Wt[128][68];
  __shared__ float las[128];
  __shared__ float dts[128];
  __shared__ float fqs[128];

  const int tid  = threadIdx.x;
  const int lane = tid & 63;
  const int w    = tid >> 6;
  const int c    = blockIdx.x & 31;
  const int hh   = (blockIdx.x >> 5) & 31;
  const int b    = blockIdx.x >> 10;
  const size_t m0 = (size_t)b * 4096 + c * QCH;
  const int slot  = (b * 32 + hh) * NCH + c;

  // ---- stage X, B^T, C^T, dt, dtA ----
  {
    const int r = tid & 127, piece = tid >> 7;
    const float* rowp = conv + (m0 + r) * CSTRIDE;
    #pragma unroll
    for (int f = 0; f < 8; ++f) {
      const int c0 = piece * 32 + f * 4;
      float4 v = *(const float4*)(rowp + hh * 64 + c0);
      Xs[r][c0] = v.x; Xs[r][c0+1] = v.y; Xs[r][c0+2] = v.z; Xs[r][c0+3] = v.w;
    }
    #pragma unroll
    for (int f = 0; f < 8; ++f) {
      const int n0 = piece * 32 + f * 4;
      float4 v = *(const float4*)(rowp + 2048 + n0);
      Bt[n0][r] = v.x; Bt[n0+1][r] = v.y; Bt[n0+2][r] = v.z; Bt[n0+3][r] = v.w;
    }
    #pragma unroll
    for (int f = 0; f < 8; ++f) {
      const int n0 = piece * 32 + f * 4;
      float4 v = *(const float4*)(rowp + 2112 + n0);
      Ct[n0][r] = v.x; Ct[n0+1][r] = v.y; Ct[n0+2][r] = v.z; Ct[n0+3][r] = v.w;
    }
    if (tid < 128) {
      dts[tid] = dtb[(m0 + tid) * 32 + hh];
      las[tid] = dtAb[(m0 + tid) * 32 + hh];
    }
  }
  __syncthreads();

  // ---- inclusive prefix sum of dtA -> la ----
  for (int ofs = 1; ofs < 128; ofs <<= 1) {
    float v = 0.f;
    if (tid < 128 && tid >= ofs) v = las[tid - ofs];
    __syncthreads();
    if (tid < 128) las[tid] += v;
    __syncthreads();
  }
  if (tid < 128) fqs[tid] = __expf(las[127] - las[tid]) * dts[tid];
  __syncthreads();

  // ---- G / W / Y in two 64-row blocks ----
  #pragma unroll
  for (int rb = 0; rb < 2; ++rb) {
    const int r0 = rb * 64 + w * 16;
    float g0[16], g1[16];
    #pragma unroll
    for (int r = 0; r < 16; ++r) { g0[r] = 0.f; g1[r] = 0.f; }
    #pragma unroll 2
    for (int n = 0; n < 64; ++n) {
      const float b0 = Bt[n][lane];
      const float b1 = Bt[n][lane + 64];
      #pragma unroll
      for (int r4 = 0; r4 < 4; ++r4) {
        float4 c4 = *(const float4*)&Ct[n][r0 + r4 * 4];
        g0[r4*4+0] = fmaf(c4.x, b0, g0[r4*4+0]); g1[r4*4+0] = fmaf(c4.x, b1, g1[r4*4+0]);
        g0[r4*4+1] = fmaf(c4.y, b0, g0[r4*4+1]); g1[r4*4+1] = fmaf(c4.y, b1, g1[r4*4+1]);
        g0[r4*4+2] = fmaf(c4.z, b0, g0[r4*4+2]); g1[r4*4+2] = fmaf(c4.z, b1, g1[r4*4+2]);
        g0[r4*4+3] = fmaf(c4.w, b0, g0[r4*4+3]); g1[r4*4+3] = fmaf(c4.w, b1, g1[r4*4+3]);
      }
    }
    const float laj0 = las[lane], laj1 = las[lane + 64];
    const float dj0 = dts[lane],  dj1 = dts[lane + 64];
    #pragma unroll
    for (int r = 0; r < 16; ++r) {
      const int i = r0 + r;
      const float la_i = las[i];
      Wt[lane][i]      = (lane <= i)      ? g0[r] * __expf(la_i - laj0) * dj0 : 0.f;
      Wt[lane + 64][i] = (lane + 64 <= i) ? g1[r] * __expf(la_i - laj1) * dj1 : 0.f;
    }
    __syncthreads();

    float y[16];
    #pragma unroll
    for (int r = 0; r < 16; ++r) y[r] = 0.f;
    #pragma unroll 2
    for (int j = 0; j < 128; ++j) {
      const float xv = Xs[j][lane];
      #pragma unroll
      for (int r4 = 0; r4 < 4; ++r4) {
        float4 w4 = *(const float4*)&Wt[j][r0 + r4 * 4];
        y[r4*4+0] = fmaf(w4.x, xv, y[r4*4+0]);
        y[r4*4+1] = fmaf(w4.y, xv, y[r4*4+1]);
        y[r4*4+2] = fmaf(w4.z, xv, y[r4*4+2]);
        y[r4*4+3] = fmaf(w4.w, xv, y[r4*4+3]);
      }
    }
    #pragma unroll
    for (int r = 0; r < 16; ++r)
      zx[(m0 + r0 + r) * LSTRIDE + 2048 + hh * 64 + lane] = y[r];
    __syncthreads();
  }

  // ---- prescale Bt rows by fq_j (conflict-free map) ----
  {
    const int j = tid & 127, nb = tid >> 7;
    const float fq = fqs[j];
    #pragma unroll
    for (int e = 0; e < 32; ++e) Bt[2 * e + nb][j] *= fq;
  }
  __syncthreads();

  // ---- S[n][p] = sum_j fq_j B[j][n] X[j][p] ----
  {
    const int nr0 = w * 16;
    float s[16];
    #pragma unroll
    for (int r = 0; r < 16; ++r) s[r] = 0.f;
    #pragma unroll 2
    for (int j = 0; j < 128; ++j) {
      const float xv = Xs[j][lane];
      #pragma unroll
      for (int r = 0; r < 16; ++r) s[r] = fmaf(Bt[nr0 + r][j], xv, s[r]);
    }
    #pragma unroll
    for (int r = 0; r < 16; ++r)
      Sbuf[(size_t)slot * 4096 + (nr0 + r) * 64 + lane] = s[r];
  }
  if (tid < 128) labuf[(size_t)slot * 128 + tid] = las[tid];
}

// --------- K4b: chunk-state recurrence; slot c := state at chunk start -----
__global__ __launch_bounds__(256) void state_scan(
    float* __restrict__ Sbuf, const float* __restrict__ labuf) {
  const int bh = blockIdx.x >> 4;
  const int e  = (blockIdx.x & 15) * 256 + threadIdx.x;
  __shared__ float cq[NCH];
  if (threadIdx.x < NCH)
    cq[threadIdx.x] = __expf(labuf[((size_t)bh * NCH + threadIdx.x) * 128 + 127]);
  __syncthreads();
  float s = 0.f;
  float* base = Sbuf + (size_t)bh * NCH * 4096 + e;
  #pragma unroll 4
  for (int c = 0; c < NCH; ++c) {
    const float sv = base[c * 4096];
    base[c * 4096] = s;
    s = fmaf(cq[c], s, sv);
  }
}

// --------- K4c: Y += exp(la_i) * C @ sin + D*x ------------------------------
__global__ __launch_bounds__(256) void chunk_out(
    const float* __restrict__ conv, const float* __restrict__ Sbuf,
    const float* __restrict__ labuf, const float* __restrict__ Dv,
    float* __restrict__ zx) {
  __shared__ float Ct[64][132];
  __shared__ float Sin[64][65];
  __shared__ float las[128];

  const int tid  = threadIdx.x;
  const int lane = tid & 63;
  const int w    = tid >> 6;
  const int c    = blockIdx.x & 31;
  const int hh   = (blockIdx.x >> 5) & 31;
  const int b    = blockIdx.x >> 10;
  const size_t m0 = (size_t)b * 4096 + c * QCH;
  const int slot  = (b * 32 + hh) * NCH + c;

  {
    const int r = tid & 127, piece = tid >> 7;
    const float* rowp = conv + (m0 + r) * CSTRIDE;
    #pragma unroll
    for (int f = 0; f < 8; ++f) {
      const int n0 = piece * 32 + f * 4;
      float4 v = *(const float4*)(rowp + 2112 + n0);
      Ct[n0][r] = v.x; Ct[n0+1][r] = v.y; Ct[n0+2][r] = v.z; Ct[n0+3][r] = v.w;
    }
    #pragma unroll
    for (int f = 0; f < 4; ++f) {
      const int idx = tid * 16 + f * 4;
      float4 v = *(const float4*)(Sbuf + (size_t)slot * 4096 + idx);
      const int n = idx >> 6, p = idx & 63;
      Sin[n][p] = v.x; Sin[n][p+1] = v.y; Sin[n][p+2] = v.z; Sin[n][p+3] = v.w;
    }
    if (tid < 128) las[tid] = labuf[(size_t)slot * 128 + tid];
  }
  __syncthreads();

  const int r0 = w * 32;
  float acc[32];
  #pragma unroll
  for (int r = 0; r < 32; ++r) acc[r] = 0.f;
  #pragma unroll 2
  for (int n = 0; n < 64; ++n) {
    const float sv = Sin[n][lane];
    #pragma unroll
    for (int r4 = 0; r4 < 8; ++r4) {
      float4 c4 = *(const float4*)&Ct[n][r0 + r4 * 4];
      acc[r4*4+0] = fmaf(c4.x, sv, acc[r4*4+0]);
      acc[r4*4+1] = fmaf(c4.y, sv, acc[r4*4+1]);
      acc[r4*4+2] = fmaf(c4.z, sv, acc[r4*4+2]);
      acc[r4*4+3] = fmaf(c4.w, sv, acc[r4*4+3]);
    }
  }
  const float Dh = Dv[hh];
  #pragma unroll
  for (int r = 0; r < 32; ++r) {
    const int i = r0 + r;
    const size_t off = (m0 + i) * LSTRIDE + 2048 + hh * 64 + lane;
    const float xv = conv[(m0 + i) * CSTRIDE + hh * 64 + lane];
    zx[off] = zx[off] + __expf(las[i]) * acc[r] + Dh * xv;
  }
}

// --------- K4f: fallback serial scan (if ws too small for chunked) ---------
__global__ __launch_bounds__(256) void scan_kernel_fb(
    const float* __restrict__ conv, const float* __restrict__ dt_buf,
    const float* __restrict__ dtA_buf, const float* __restrict__ Dv,
    float* __restrict__ yout) {
  const int wid  = blockIdx.x * 4 + (threadIdx.x >> 6);
  const int lane = threadIdx.x & 63;
  const int b = wid >> 11;
  const int h = (wid >> 6) & 31;
  const int p = wid & 63;
  const size_t m0 = (size_t)b * 4096;
  const float* cx  = conv + m0 * CSTRIDE + h * 64 + p;
  const float* cB  = conv + m0 * CSTRIDE + 2048 + lane;
  const float* cC  = cB + 64;
  const float* cdA = dtA_buf + m0 * 32 + h;
  const float* cdt = dt_buf + m0 * 32 + h;
  float* yo = yout + m0 * LSTRIDE + 2048 + h * 64 + p;
  const float Dh = Dv[h];
  float s = 0.f;
  #pragma unroll 2
  for (int t = 0; t < 4096; ++t) {
    float xv  = cx[(size_t)t * CSTRIDE];
    float Bv  = cB[(size_t)t * CSTRIDE];
    float Cv  = cC[(size_t)t * CSTRIDE];
    float dAv = __expf(cdA[t * 32]);
    float dtv = cdt[t * 32];
    s = fmaf(s, dAv, dtv * xv * Bv);
    float prod = s * Cv;
    #pragma unroll
    for (int msk = 1; msk < 64; msk <<= 1) prod += __shfl_xor(prod, msk, 64);
    if (lane == 0) yo[(size_t)t * LSTRIDE] = fmaf(Dh, xv, prod);
  }
}

// ----------------- K5: gate with silu(z) + RMSNorm (in place) --------------
__global__ __launch_bounds__(256) void norm_kernel(
    float* __restrict__ zx, const float* __restrict__ nw) {
  const int row = blockIdx.x, tid = threadIdx.x;
  float* z = zx + (size_t)row * LSTRIDE;
  float* y = z + 2048;
  float g[8];
  float ss = 0.f;
  #pragma unroll
  for (int j = 0; j < 2; ++j) {
    const int col = j * 1024 + tid * 4;
    float4 yv = *(const float4*)&y[col];
    float4 zv = *(const float4*)&z[col];
    float gs[4];
    gs[0] = yv.x * (zv.x / (1.f + expf(-zv.x)));
    gs[1] = yv.y * (zv.y / (1.f + expf(-zv.y)));
    gs[2] = yv.z * (zv.z / (1.f + expf(-zv.z)));
    gs[3] = yv.w * (zv.w / (1.f + expf(-zv.w)));
    #pragma unroll
    for (int q = 0; q < 4; ++q) { g[j * 4 + q] = gs[q]; ss += gs[q] * gs[q]; }
  }
  #pragma unroll
  for (int msk = 1; msk < 64; msk <<= 1) ss += __shfl_xor(ss, msk, 64);
  __shared__ float sred[4];
  if ((tid & 63) == 0) sred[tid >> 6] = ss;
  __syncthreads();
  ss = sred[0] + sred[1] + sred[2] + sred[3];
  const float scale = rsqrtf(ss * (1.f / 2048.f) + 1e-5f);
  #pragma unroll
  for (int j = 0; j < 2; ++j) {
    const int col = j * 1024 + tid * 4;
    float4 ov;
    ov.x = g[j * 4 + 0] * scale * nw[col + 0];
    ov.y = g[j * 4 + 1] * scale * nw[col + 1];
    ov.z = g[j * 4 + 2] * scale * nw[col + 2];
    ov.w = g[j * 4 + 3] * scale * nw[col + 3];
    *(float4*)&y[col] = ov;
  }
}

// ---------------------------------------------------------------------------
extern "C" void kernel_launch(void* const* d_in, const int* in_sizes, int n_in,
                              void* d_out, int out_size, void* d_ws, size_t ws_size,
                              hipStream_t stream) {
  const float* x       = (const float*)d_in[0];
  const float* W_in    = (const float*)d_in[1];
  const float* conv_w  = (const float*)d_in[2];
  const float* conv_b  = (const float*)d_in[3];
  const float* dt_bias = (const float*)d_in[4];
  const float* A_log   = (const float*)d_in[5];
  const float* Dv      = (const float*)d_in[6];
  const float* nw      = (const float*)d_in[7];
  const float* W_out   = (const float*)d_in[8];
  float* out = (float*)d_out;

  float* zx    = (float*)d_ws;
  float* conv  = zx + (size_t)MROWS * LSTRIDE;       // +34,603,008
  float* dtb   = conv + (size_t)MROWS * CSTRIDE;     // +17,825,792
  float* dtAb  = dtb + (size_t)MROWS * 32;           // +262,144
  float* Sbuf  = dtAb + (size_t)MROWS * 32;          // +262,144
  float* labuf = Sbuf + (size_t)64 * NCH * 4096;     // +8,388,608

  const size_t NEED_CHUNKED = 246415360;             // bytes
  const bool chunked = (ws_size >= NEED_CHUNKED);

  gemm_bf16split<<<dim3(33, 64), 256, 0, stream>>>(x, W_in, zx, 1024, 1024, 4256, LSTRIDE);
  dt_kernel<<<MROWS, 256, 0, stream>>>(x, W_in, dt_bias, A_log, dtb, dtAb);
  conv_kernel<<<dim3(9, MROWS), 256, 0, stream>>>(zx, conv_w, conv_b, conv);

  if (chunked) {
    chunk_intra<<<2048, 256, 0, stream>>>(conv, dtb, dtAb, zx, Sbuf, labuf);
    state_scan<<<1024, 256, 0, stream>>>(Sbuf, labuf);
    chunk_out<<<2048, 256, 0, stream>>>(conv, Sbuf, labuf, Dv, zx);
  } else {
    scan_kernel_fb<<<1024, 256, 0, stream>>>(conv, dtb, dtAb, Dv, zx);
  }

  norm_kernel<<<MROWS, 256, 0, stream>>>(zx, nw);
  gemm_bf16split<<<dim3(8, 64), 256, 0, stream>>>(zx + 2048, W_out, out, 2048, LSTRIDE, 1024, 1024);
}

// Round 6
// 834.259 us; speedup vs baseline: 3.2760x; 1.2284x over previous
//
#include <hip/hip_runtime.h>
#include <hip/hip_bf16.h>
#include <math.h>

// ---------------------------------------------------------------------------
// Mamba2 forward. Split-bf16 MFMA GEMMs + MFMA chunked (SSD) scan.
// Shapes: B=2 L=4096 DM=1024 DI=2048 DS=64 HD=64 NH=32 DCONV=4
// Pipeline:
//   K1 gemm_bf16split: zx[m,0:4224] = x @ W_in[:,0:4224]
//   K2 dt_kernel     : dt=softplus(x·w+b); dtA = dt*A
//   K3 conv_kernel   : conv = silu(depthwise causal conv4 + bias)
//   K4a chunk_intra  : per (b,h,c) Q=128 tile, ALL-MFMA (split-bf16 3-pass):
//                      G=C@B^T -> mask*exp -> W;  Y=W@X;  S=(fq·B)^T@X
//   K4b state_scan   : inter-chunk recurrence (elementwise)
//   K4c chunk_out    : Y += exp(la_i)*C@sin + D*x
//   K5 norm_kernel   : g=y*silu(z); RMSNorm(g)*w
//   K6 gemm_bf16split: out = yn @ W_out
// chunk_intra LDS: pool1 64KB (C/B hi/lo -> reused for W hi/lo),
//                  pool2 64KB (Xt/Btf hi/lo), ~1.5KB scalars. Peak ~130KB.
// XOR swizzle (k ^= (row&7)<<3, ushort units) keeps frag ds_read_b128 2-way.
// ws (floats): zx | conv | dt | dtA | S | la  => 246,415,360 bytes.
// ---------------------------------------------------------------------------

#define LSTRIDE 4224
#define CSTRIDE 2176
#define MROWS   8192
#define LPAD    40
#define QCH     128
#define NCH     32

typedef __attribute__((ext_vector_type(8))) short bf16x8;
typedef __attribute__((ext_vector_type(4))) float f32x4;

static __device__ __forceinline__ ushort f2bf_rne(float f) {
  unsigned u = __float_as_uint(f);
  unsigned r = (u + 0x7fffu + ((u >> 16) & 1u)) >> 16;
  return (ushort)r;
}
static __device__ __forceinline__ float bf2f(ushort u) {
  return __uint_as_float(((unsigned)u) << 16);
}
static __device__ __forceinline__ void split4(float4 v, ushort4& h, ushort4& l) {
  h.x = f2bf_rne(v.x); l.x = f2bf_rne(v.x - bf2f(h.x));
  h.y = f2bf_rne(v.y); l.y = f2bf_rne(v.y - bf2f(h.y));
  h.z = f2bf_rne(v.z); l.z = f2bf_rne(v.z - bf2f(h.z));
  h.w = f2bf_rne(v.w); l.w = f2bf_rne(v.w - bf2f(h.w));
}

// swizzled indices: 2-way-max bank aliasing on 16B frag reads
#define CBI(r,k) ((r)*64  + ((k) ^ (((r)&7)<<3)))   // [128][64] ushort
#define TXI(p,j) ((p)*128 + ((j) ^ (((p)&7)<<3)))   // [64|128][128] ushort

// ------- K1/K6: split-bf16 MFMA GEMM, 128x128 tile, 4 waves of 64x64 -------
__global__ __launch_bounds__(256) void gemm_bf16split(
    const float* __restrict__ A, const float* __restrict__ B,
    float* __restrict__ C, int K, int lda, int ldb, int ldc) {
  __shared__ ushort Ah[128][LPAD];
  __shared__ ushort Al[128][LPAD];
  __shared__ ushort Bh[128][LPAD];
  __shared__ ushort Bl[128][LPAD];

  const int tid  = threadIdx.x;
  const int lane = tid & 63;
  const int wid  = tid >> 6;
  const int wm   = wid >> 1;
  const int wn   = wid & 1;
  const int bm   = blockIdx.y * 128;
  const int bn   = blockIdx.x * 128;

  const int ar  = tid >> 1;
  const int acg = (tid & 1) * 16;
  const int bnt = tid & 127;
  const int bkg = (tid >> 7) * 16;

  const int lr  = lane & 15;
  const int lk8 = (lane >> 4) * 8;
  const int lq4 = (lane >> 4) * 4;

  f32x4 acc[4][4];
  #pragma unroll
  for (int m = 0; m < 4; ++m)
    #pragma unroll
    for (int n = 0; n < 4; ++n) acc[m][n] = (f32x4)0.f;

  for (int k0 = 0; k0 < K; k0 += 32) {
    float4 av[4];
    #pragma unroll
    for (int f = 0; f < 4; ++f)
      av[f] = *(const float4*)(A + (size_t)(bm + ar) * lda + k0 + acg + f * 4);
    float bv[16];
    #pragma unroll
    for (int kk = 0; kk < 16; ++kk)
      bv[kk] = B[(size_t)(k0 + bkg + kk) * ldb + bn + bnt];

    __syncthreads();

    #pragma unroll
    for (int f = 0; f < 4; ++f) {
      const int col = acg + f * 4;
      ushort4 h, l;
      split4(av[f], h, l);
      *(ushort4*)&Ah[ar][col] = h;
      *(ushort4*)&Al[ar][col] = l;
    }
    {
      ushort h[16], l[16];
      #pragma unroll
      for (int kk = 0; kk < 16; ++kk) {
        h[kk] = f2bf_rne(bv[kk]);
        l[kk] = f2bf_rne(bv[kk] - bf2f(h[kk]));
      }
      #pragma unroll
      for (int f = 0; f < 4; ++f) {
        *(ushort4*)&Bh[bnt][bkg + f * 4] = make_ushort4(h[f*4], h[f*4+1], h[f*4+2], h[f*4+3]);
        *(ushort4*)&Bl[bnt][bkg + f * 4] = make_ushort4(l[f*4], l[f*4+1], l[f*4+2], l[f*4+3]);
      }
    }
    __syncthreads();

    bf16x8 fah[4], fal[4], fbh[4], fbl[4];
    #pragma unroll
    for (int m = 0; m < 4; ++m) {
      const int row = wm * 64 + m * 16 + lr;
      fah[m] = *(const bf16x8*)&Ah[row][lk8];
      fal[m] = *(const bf16x8*)&Al[row][lk8];
    }
    #pragma unroll
    for (int n = 0; n < 4; ++n) {
      const int col = wn * 64 + n * 16 + lr;
      fbh[n] = *(const bf16x8*)&Bh[col][lk8];
      fbl[n] = *(const bf16x8*)&Bl[col][lk8];
    }
    #pragma unroll
    for (int m = 0; m < 4; ++m)
      #pragma unroll
      for (int n = 0; n < 4; ++n) {
        acc[m][n] = __builtin_amdgcn_mfma_f32_16x16x32_bf16(fah[m], fbh[n], acc[m][n], 0, 0, 0);
        acc[m][n] = __builtin_amdgcn_mfma_f32_16x16x32_bf16(fah[m], fbl[n], acc[m][n], 0, 0, 0);
        acc[m][n] = __builtin_amdgcn_mfma_f32_16x16x32_bf16(fal[m], fbh[n], acc[m][n], 0, 0, 0);
      }
  }

  #pragma unroll
  for (int m = 0; m < 4; ++m) {
    const int rbase = bm + wm * 64 + m * 16 + lq4;
    #pragma unroll
    for (int n = 0; n < 4; ++n) {
      const int col = bn + wn * 64 + n * 16 + lr;
      #pragma unroll
      for (int q = 0; q < 4; ++q)
        C[(size_t)(rbase + q) * ldc + col] = acc[m][n][q];
    }
  }
}

// ----------------- K2: dt columns (fp32 dot) + softplus + dtA --------------
__global__ __launch_bounds__(256) void dt_kernel(
    const float* __restrict__ x, const float* __restrict__ W_in,
    const float* __restrict__ dt_bias, const float* __restrict__ A_log,
    float* __restrict__ dt_buf, float* __restrict__ dtA_buf) {
  __shared__ float xs[1024];
  __shared__ float red[8][32];
  const int m = blockIdx.x, tid = threadIdx.x;
  const float* xr = x + (size_t)m * 1024;
  *(float4*)&xs[tid * 4] = *(const float4*)&xr[tid * 4];
  __syncthreads();
  const int h = tid & 31, part = tid >> 5;
  const float* w = W_in + 4224 + h;
  float acc = 0.f;
  const int kb = part * 128;
  #pragma unroll 4
  for (int k = kb; k < kb + 128; ++k) acc = fmaf(xs[k], w[(size_t)k * 4256], acc);
  red[part][h] = acc;
  __syncthreads();
  if (tid < 32) {
    float v = 0.f;
    #pragma unroll
    for (int p = 0; p < 8; ++p) v += red[p][tid];
    v += dt_bias[tid];
    float sp = v > 20.f ? v : log1pf(expf(v));
    float An = -expf(A_log[tid]);
    dt_buf[(size_t)m * 32 + tid] = sp;
    dtA_buf[(size_t)m * 32 + tid] = sp * An;
  }
}

// ----------------- K3: causal depthwise conv4 + bias + silu ----------------
__global__ __launch_bounds__(256) void conv_kernel(
    const float* __restrict__ zx, const float* __restrict__ cw,
    const float* __restrict__ cb, float* __restrict__ conv) {
  const int c = blockIdx.x * 256 + threadIdx.x;
  if (c >= CSTRIDE) return;
  const int m = blockIdx.y;
  const int l = m & 4095;
  float acc = cb[c];
  const float* src = zx + (size_t)m * LSTRIDE + 2048 + c;
  #pragma unroll
  for (int k = 0; k < 4; ++k) {
    int lk = l - 3 + k;
    if (lk >= 0) acc = fmaf(src[(size_t)(k - 3) * LSTRIDE], cw[c * 4 + k], acc);
  }
  float s = acc / (1.f + expf(-acc));
  conv[(size_t)m * CSTRIDE + c] = s;
}

// --------- K4a: intra-chunk, all-MFMA (split-bf16 3-pass) ------------------
__global__ __launch_bounds__(256) void chunk_intra(
    const float* __restrict__ conv, const float* __restrict__ dtb,
    const float* __restrict__ dtAb, float* __restrict__ zx,
    float* __restrict__ Sbuf, float* __restrict__ labuf) {
  __shared__ ushort pool1[32768];   // C/B hi/lo -> later W hi/lo (64KB)
  __shared__ ushort pool2[32768];   // Xt/Btf hi/lo (64KB)
  __shared__ float las[128], dts[128], fqs[128];

  ushort* Chi = pool1;
  ushort* Clo = pool1 + 8192;
  ushort* Bhi = pool1 + 16384;
  ushort* Blo = pool1 + 24576;
  ushort* Whi = pool1;              // aliases C region after barrier
  ushort* Wlo = pool1 + 16384;      // aliases B region
  ushort* Xth = pool2;
  ushort* Xtl = pool2 + 8192;
  ushort* Bfh = pool2 + 16384;
  ushort* Bfl = pool2 + 24576;

  const int tid  = threadIdx.x;
  const int lane = tid & 63;
  const int w    = tid >> 6;
  const int l15  = lane & 15;
  const int l4   = lane >> 4;
  const int c    = blockIdx.x & 31;
  const int hh   = (blockIdx.x >> 5) & 31;
  const int b    = blockIdx.x >> 10;
  const size_t m0 = (size_t)b * 4096 + c * QCH;
  const int slot  = (b * 32 + hh) * NCH + c;

  // ---- phase A: dt/dtA, prefix-sum -> la, fq; write labuf ----
  if (tid < 128) {
    dts[tid] = dtb[(m0 + tid) * 32 + hh];
    las[tid] = dtAb[(m0 + tid) * 32 + hh];
  }
  __syncthreads();
  for (int ofs = 1; ofs < 128; ofs <<= 1) {
    float v = 0.f;
    if (tid < 128 && tid >= ofs) v = las[tid - ofs];
    __syncthreads();
    if (tid < 128) las[tid] += v;
    __syncthreads();
  }
  if (tid < 128) {
    fqs[tid] = __expf(las[127] - las[tid]) * dts[tid];
    labuf[(size_t)slot * 128 + tid] = las[tid];
  }
  __syncthreads();

  // ---- phase B: stage C,B (row-major) + Xt,Btf (transposed), bf16 hi/lo ----
  {
    const int r = tid & 127, hf = tid >> 7;
    const float* rowp = conv + (m0 + r) * CSTRIDE;
    const float fqr = fqs[r];
    #pragma unroll
    for (int f = 0; f < 8; ++f) {
      const int c0 = hf * 32 + f * 4;
      float4 vc = *(const float4*)(rowp + 2112 + c0);
      ushort4 h, l;
      split4(vc, h, l);
      *(ushort4*)(Chi + CBI(r, c0)) = h;
      *(ushort4*)(Clo + CBI(r, c0)) = l;
      float4 vb = *(const float4*)(rowp + 2048 + c0);
      split4(vb, h, l);
      *(ushort4*)(Bhi + CBI(r, c0)) = h;
      *(ushort4*)(Blo + CBI(r, c0)) = l;
      float fb[4] = {vb.x * fqr, vb.y * fqr, vb.z * fqr, vb.w * fqr};
      #pragma unroll
      for (int e = 0; e < 4; ++e) {
        ushort hh2 = f2bf_rne(fb[e]);
        Bfh[TXI(c0 + e, r)] = hh2;
        Bfl[TXI(c0 + e, r)] = f2bf_rne(fb[e] - bf2f(hh2));
      }
      float4 vx = *(const float4*)(rowp + hh * 64 + c0);
      float fx[4] = {vx.x, vx.y, vx.z, vx.w};
      #pragma unroll
      for (int e = 0; e < 4; ++e) {
        ushort hh2 = f2bf_rne(fx[e]);
        Xth[TXI(c0 + e, r)] = hh2;
        Xtl[TXI(c0 + e, r)] = f2bf_rne(fx[e] - bf2f(hh2));
      }
    }
  }
  __syncthreads();

  // ---- matmul 1: G = C @ B^T  (wave w owns rows [32w,32w+32), all 128 cols)
  f32x4 g[2][8];
  #pragma unroll
  for (int ti = 0; ti < 2; ++ti)
    #pragma unroll
    for (int tj = 0; tj < 8; ++tj) g[ti][tj] = (f32x4)0.f;

  #pragma unroll
  for (int ks = 0; ks < 2; ++ks) {
    const int kb = ks * 32 + l4 * 8;
    bf16x8 ca[2][2], bb[8][2];
    #pragma unroll
    for (int ti = 0; ti < 2; ++ti) {
      const int row = 32 * w + ti * 16 + l15;
      ca[ti][0] = *(const bf16x8*)(Chi + CBI(row, kb));
      ca[ti][1] = *(const bf16x8*)(Clo + CBI(row, kb));
    }
    #pragma unroll
    for (int tj = 0; tj < 8; ++tj) {
      const int jr = tj * 16 + l15;
      bb[tj][0] = *(const bf16x8*)(Bhi + CBI(jr, kb));
      bb[tj][1] = *(const bf16x8*)(Blo + CBI(jr, kb));
    }
    #pragma unroll
    for (int ti = 0; ti < 2; ++ti)
      #pragma unroll
      for (int tj = 0; tj < 8; ++tj) {
        g[ti][tj] = __builtin_amdgcn_mfma_f32_16x16x32_bf16(ca[ti][0], bb[tj][0], g[ti][tj], 0, 0, 0);
        g[ti][tj] = __builtin_amdgcn_mfma_f32_16x16x32_bf16(ca[ti][0], bb[tj][1], g[ti][tj], 0, 0, 0);
        g[ti][tj] = __builtin_amdgcn_mfma_f32_16x16x32_bf16(ca[ti][1], bb[tj][0], g[ti][tj], 0, 0, 0);
      }
  }
  __syncthreads();   // all waves done reading C/B before W overwrites

  // ---- mask: W[i][j] = (j<=i) ? G*exp(la_i-la_j)*dt_j : 0 ; write bf16 hi/lo
  #pragma unroll
  for (int ti = 0; ti < 2; ++ti) {
    const int ib = 32 * w + ti * 16 + l4 * 4;
    #pragma unroll
    for (int tj = 0; tj < 8; ++tj) {
      const int j = tj * 16 + l15;
      const float laj = las[j], dj = dts[j];
      #pragma unroll
      for (int q = 0; q < 4; ++q) {
        const int i = ib + q;
        float wv = (j <= i) ? g[ti][tj][q] * __expf(las[i] - laj) * dj : 0.f;
        ushort h = f2bf_rne(wv);
        Whi[TXI(i, j)] = h;
        Wlo[TXI(i, j)] = f2bf_rne(wv - bf2f(h));
      }
    }
  }
  // no barrier: wave reads only the W rows it wrote

  // ---- matmul 2: Y = W @ X  (rows [32w,32w+32) x 64 cols) ----
  f32x4 y[2][4];
  #pragma unroll
  for (int ti = 0; ti < 2; ++ti)
    #pragma unroll
    for (int tp = 0; tp < 4; ++tp) y[ti][tp] = (f32x4)0.f;

  #pragma unroll
  for (int ks = 0; ks < 4; ++ks) {
    const int kb = ks * 32 + l4 * 8;
    bf16x8 wa[2][2], xb[4][2];
    #pragma unroll
    for (int ti = 0; ti < 2; ++ti) {
      const int row = 32 * w + ti * 16 + l15;
      wa[ti][0] = *(const bf16x8*)(Whi + TXI(row, kb));
      wa[ti][1] = *(const bf16x8*)(Wlo + TXI(row, kb));
    }
    #pragma unroll
    for (int tp = 0; tp < 4; ++tp) {
      const int p = tp * 16 + l15;
      xb[tp][0] = *(const bf16x8*)(Xth + TXI(p, kb));
      xb[tp][1] = *(const bf16x8*)(Xtl + TXI(p, kb));
    }
    #pragma unroll
    for (int ti = 0; ti < 2; ++ti)
      #pragma unroll
      for (int tp = 0; tp < 4; ++tp) {
        y[ti][tp] = __builtin_amdgcn_mfma_f32_16x16x32_bf16(wa[ti][0], xb[tp][0], y[ti][tp], 0, 0, 0);
        y[ti][tp] = __builtin_amdgcn_mfma_f32_16x16x32_bf16(wa[ti][0], xb[tp][1], y[ti][tp], 0, 0, 0);
        y[ti][tp] = __builtin_amdgcn_mfma_f32_16x16x32_bf16(wa[ti][1], xb[tp][0], y[ti][tp], 0, 0, 0);
      }
  }
  #pragma unroll
  for (int ti = 0; ti < 2; ++ti) {
    #pragma unroll
    for (int tp = 0; tp < 4; ++tp) {
      const int p = tp * 16 + l15;
      #pragma unroll
      for (int q = 0; q < 4; ++q) {
        const int i = 32 * w + ti * 16 + l4 * 4 + q;
        zx[(m0 + i) * LSTRIDE + 2048 + hh * 64 + p] = y[ti][tp][q];
      }
    }
  }

  // ---- matmul 3: S^T = Xt @ (fq·B)  (wave w owns p-rows [16w,16w+16)) ----
  f32x4 s[4];
  #pragma unroll
  for (int tn = 0; tn < 4; ++tn) s[tn] = (f32x4)0.f;
  #pragma unroll
  for (int ks = 0; ks < 4; ++ks) {
    const int kb = ks * 32 + l4 * 8;
    bf16x8 xa[2], bf[4][2];
    {
      const int p = 16 * w + l15;
      xa[0] = *(const bf16x8*)(Xth + TXI(p, kb));
      xa[1] = *(const bf16x8*)(Xtl + TXI(p, kb));
    }
    #pragma unroll
    for (int tn = 0; tn < 4; ++tn) {
      const int n = tn * 16 + l15;
      bf[tn][0] = *(const bf16x8*)(Bfh + TXI(n, kb));
      bf[tn][1] = *(const bf16x8*)(Bfl + TXI(n, kb));
    }
    #pragma unroll
    for (int tn = 0; tn < 4; ++tn) {
      s[tn] = __builtin_amdgcn_mfma_f32_16x16x32_bf16(xa[0], bf[tn][0], s[tn], 0, 0, 0);
      s[tn] = __builtin_amdgcn_mfma_f32_16x16x32_bf16(xa[0], bf[tn][1], s[tn], 0, 0, 0);
      s[tn] = __builtin_amdgcn_mfma_f32_16x16x32_bf16(xa[1], bf[tn][0], s[tn], 0, 0, 0);
    }
  }
  #pragma unroll
  for (int tn = 0; tn < 4; ++tn) {
    const int n = tn * 16 + l15;
    #pragma unroll
    for (int q = 0; q < 4; ++q) {
      const int p = 16 * w + l4 * 4 + q;
      Sbuf[(size_t)slot * 4096 + n * 64 + p] = s[tn][q];
    }
  }
}

// --------- K4b: chunk-state recurrence; slot c := state at chunk start -----
__global__ __launch_bounds__(256) void state_scan(
    float* __restrict__ Sbuf, const float* __restrict__ labuf) {
  const int bh = blockIdx.x >> 4;
  const int e  = (blockIdx.x & 15) * 256 + threadIdx.x;
  __shared__ float cq[NCH];
  if (threadIdx.x < NCH)
    cq[threadIdx.x] = __expf(labuf[((size_t)bh * NCH + threadIdx.x) * 128 + 127]);
  __syncthreads();
  float s = 0.f;
  float* base = Sbuf + (size_t)bh * NCH * 4096 + e;
  #pragma unroll 4
  for (int c = 0; c < NCH; ++c) {
    const float sv = base[c * 4096];
    base[c * 4096] = s;
    s = fmaf(cq[c], s, sv);
  }
}

// --------- K4c: Y += exp(la_i) * C @ sin + D*x ------------------------------
__global__ __launch_bounds__(256) void chunk_out(
    const float* __restrict__ conv, const float* __restrict__ Sbuf,
    const float* __restrict__ labuf, const float* __restrict__ Dv,
    float* __restrict__ zx) {
  __shared__ float Ct[64][132];
  __shared__ float Sin[64][65];
  __shared__ float las[128];

  const int tid  = threadIdx.x;
  const int lane = tid & 63;
  const int w    = tid >> 6;
  const int c    = blockIdx.x & 31;
  const int hh   = (blockIdx.x >> 5) & 31;
  const int b    = blockIdx.x >> 10;
  const size_t m0 = (size_t)b * 4096 + c * QCH;
  const int slot  = (b * 32 + hh) * NCH + c;

  {
    const int r = tid & 127, piece = tid >> 7;
    const float* rowp = conv + (m0 + r) * CSTRIDE;
    #pragma unroll
    for (int f = 0; f < 8; ++f) {
      const int n0 = piece * 32 + f * 4;
      float4 v = *(const float4*)(rowp + 2112 + n0);
      Ct[n0][r] = v.x; Ct[n0+1][r] = v.y; Ct[n0+2][r] = v.z; Ct[n0+3][r] = v.w;
    }
    #pragma unroll
    for (int f = 0; f < 4; ++f) {
      const int idx = tid * 16 + f * 4;
      float4 v = *(const float4*)(Sbuf + (size_t)slot * 4096 + idx);
      const int n = idx >> 6, p = idx & 63;
      Sin[n][p] = v.x; Sin[n][p+1] = v.y; Sin[n][p+2] = v.z; Sin[n][p+3] = v.w;
    }
    if (tid < 128) las[tid] = labuf[(size_t)slot * 128 + tid];
  }
  __syncthreads();

  const int r0 = w * 32;
  float acc[32];
  #pragma unroll
  for (int r = 0; r < 32; ++r) acc[r] = 0.f;
  #pragma unroll 2
  for (int n = 0; n < 64; ++n) {
    const float sv = Sin[n][lane];
    #pragma unroll
    for (int r4 = 0; r4 < 8; ++r4) {
      float4 c4 = *(const float4*)&Ct[n][r0 + r4 * 4];
      acc[r4*4+0] = fmaf(c4.x, sv, acc[r4*4+0]);
      acc[r4*4+1] = fmaf(c4.y, sv, acc[r4*4+1]);
      acc[r4*4+2] = fmaf(c4.z, sv, acc[r4*4+2]);
      acc[r4*4+3] = fmaf(c4.w, sv, acc[r4*4+3]);
    }
  }
  const float Dh = Dv[hh];
  #pragma unroll
  for (int r = 0; r < 32; ++r) {
    const int i = r0 + r;
    const size_t off = (m0 + i) * LSTRIDE + 2048 + hh * 64 + lane;
    const float xv = conv[(m0 + i) * CSTRIDE + hh * 64 + lane];
    zx[off] = zx[off] + __expf(las[i]) * acc[r] + Dh * xv;
  }
}

// --------- K4f: fallback serial scan (if ws too small for chunked) ---------
__global__ __launch_bounds__(256) void scan_kernel_fb(
    const float* __restrict__ conv, const float* __restrict__ dt_buf,
    const float* __restrict__ dtA_buf, const float* __restrict__ Dv,
    float* __restrict__ yout) {
  const int wid  = blockIdx.x * 4 + (threadIdx.x >> 6);
  const int lane = threadIdx.x & 63;
  const int b = wid >> 11;
  const int h = (wid >> 6) & 31;
  const int p = wid & 63;
  const size_t m0 = (size_t)b * 4096;
  const float* cx  = conv + m0 * CSTRIDE + h * 64 + p;
  const float* cB  = conv + m0 * CSTRIDE + 2048 + lane;
  const float* cC  = cB + 64;
  const float* cdA = dtA_buf + m0 * 32 + h;
  const float* cdt = dt_buf + m0 * 32 + h;
  float* yo = yout + m0 * LSTRIDE + 2048 + h * 64 + p;
  const float Dh = Dv[h];
  float s = 0.f;
  #pragma unroll 2
  for (int t = 0; t < 4096; ++t) {
    float xv  = cx[(size_t)t * CSTRIDE];
    float Bv  = cB[(size_t)t * CSTRIDE];
    float Cv  = cC[(size_t)t * CSTRIDE];
    float dAv = __expf(cdA[t * 32]);
    float dtv = cdt[t * 32];
    s = fmaf(s, dAv, dtv * xv * Bv);
    float prod = s * Cv;
    #pragma unroll
    for (int msk = 1; msk < 64; msk <<= 1) prod += __shfl_xor(prod, msk, 64);
    if (lane == 0) yo[(size_t)t * LSTRIDE] = fmaf(Dh, xv, prod);
  }
}

// ----------------- K5: gate with silu(z) + RMSNorm (in place) --------------
__global__ __launch_bounds__(256) void norm_kernel(
    float* __restrict__ zx, const float* __restrict__ nw) {
  const int row = blockIdx.x, tid = threadIdx.x;
  float* z = zx + (size_t)row * LSTRIDE;
  float* y = z + 2048;
  float g[8];
  float ss = 0.f;
  #pragma unroll
  for (int j = 0; j < 2; ++j) {
    const int col = j * 1024 + tid * 4;
    float4 yv = *(const float4*)&y[col];
    float4 zv = *(const float4*)&z[col];
    float gs[4];
    gs[0] = yv.x * (zv.x / (1.f + expf(-zv.x)));
    gs[1] = yv.y * (zv.y / (1.f + expf(-zv.y)));
    gs[2] = yv.z * (zv.z / (1.f + expf(-zv.z)));
    gs[3] = yv.w * (zv.w / (1.f + expf(-zv.w)));
    #pragma unroll
    for (int q = 0; q < 4; ++q) { g[j * 4 + q] = gs[q]; ss += gs[q] * gs[q]; }
  }
  #pragma unroll
  for (int msk = 1; msk < 64; msk <<= 1) ss += __shfl_xor(ss, msk, 64);
  __shared__ float sred[4];
  if ((tid & 63) == 0) sred[tid >> 6] = ss;
  __syncthreads();
  ss = sred[0] + sred[1] + sred[2] + sred[3];
  const float scale = rsqrtf(ss * (1.f / 2048.f) + 1e-5f);
  #pragma unroll
  for (int j = 0; j < 2; ++j) {
    const int col = j * 1024 + tid * 4;
    float4 ov;
    ov.x = g[j * 4 + 0] * scale * nw[col + 0];
    ov.y = g[j * 4 + 1] * scale * nw[col + 1];
    ov.z = g[j * 4 + 2] * scale * nw[col + 2];
    ov.w = g[j * 4 + 3] * scale * nw[col + 3];
    *(float4*)&y[col] = ov;
  }
}

// ---------------------------------------------------------------------------
extern "C" void kernel_launch(void* const* d_in, const int* in_sizes, int n_in,
                              void* d_out, int out_size, void* d_ws, size_t ws_size,
                              hipStream_t stream) {
  const float* x       = (const float*)d_in[0];
  const float* W_in    = (const float*)d_in[1];
  const float* conv_w  = (const float*)d_in[2];
  const float* conv_b  = (const float*)d_in[3];
  const float* dt_bias = (const float*)d_in[4];
  const float* A_log   = (const float*)d_in[5];
  const float* Dv      = (const float*)d_in[6];
  const float* nw      = (const float*)d_in[7];
  const float* W_out   = (const float*)d_in[8];
  float* out = (float*)d_out;

  float* zx    = (float*)d_ws;
  float* conv  = zx + (size_t)MROWS * LSTRIDE;
  float* dtb   = conv + (size_t)MROWS * CSTRIDE;
  float* dtAb  = dtb + (size_t)MROWS * 32;
  float* Sbuf  = dtAb + (size_t)MROWS * 32;
  float* labuf = Sbuf + (size_t)64 * NCH * 4096;

  const size_t NEED_CHUNKED = 246415360;
  const bool chunked = (ws_size >= NEED_CHUNKED);

  gemm_bf16split<<<dim3(33, 64), 256, 0, stream>>>(x, W_in, zx, 1024, 1024, 4256, LSTRIDE);
  dt_kernel<<<MROWS, 256, 0, stream>>>(x, W_in, dt_bias, A_log, dtb, dtAb);
  conv_kernel<<<dim3(9, MROWS), 256, 0, stream>>>(zx, conv_w, conv_b, conv);

  if (chunked) {
    chunk_intra<<<2048, 256, 0, stream>>>(conv, dtb, dtAb, zx, Sbuf, labuf);
    state_scan<<<1024, 256, 0, stream>>>(Sbuf, labuf);
    chunk_out<<<2048, 256, 0, stream>>>(conv, Sbuf, labuf, Dv, zx);
  } else {
    scan_kernel_fb<<<1024, 256, 0, stream>>>(conv, dtb, dtAb, Dv, zx);
  }

  norm_kernel<<<MROWS, 256, 0, stream>>>(zx, nw);
  gemm_bf16split<<<dim3(8, 64), 256, 0, stream>>>(zx + 2048, W_out, out, 2048, LSTRIDE, 1024, 1024);
}